// Round 7
// baseline (1163.229 us; speedup 1.0000x reference)
//
#include <hip/hip_runtime.h>
#include <math.h>

// Problem constants: B=16, L=512, D=1024, H=4, hd=256, BL = B*L = 8192.

typedef unsigned short u16;
typedef __attribute__((ext_vector_type(8))) short bf16x8;
typedef __attribute__((ext_vector_type(4))) float f32x4;

// Split fp32 into bf16 hi + bf16 lo (RNE both). x ~= hi + lo with ~2^-16 rel err.
__device__ inline void split2(float x, u16& h, u16& l) {
    union F { float f; unsigned int u; };
    F a; a.f = x;
    unsigned int hu = (a.u + 0x7FFFu + ((a.u >> 16) & 1u)) & 0xFFFF0000u;
    h = (u16)(hu >> 16);
    F hf; hf.u = hu;
    F r; r.f = x - hf.f;
    l = (u16)((r.u + 0x7FFFu + ((r.u >> 16) & 1u)) >> 16);
}

// Async global->LDS, 16 B per lane. LDS dest is wave-uniform base + lane*16.
__device__ inline void gload16(const void* g, void* l) {
    __builtin_amdgcn_global_load_lds(
        (const __attribute__((address_space(1))) void*)g,
        (__attribute__((address_space(3))) void*)l, 16, 0, 0);
}

// ---------------------------------------------------------------------------
// LayerNorm over rows of 1024 floats -> bf16 hi/lo planes (GEMM A operand).
// ---------------------------------------------------------------------------
__global__ __launch_bounds__(256)
void ln_split_kernel(const float* __restrict__ x, const float* __restrict__ g,
                     const float* __restrict__ b, u16* __restrict__ yh,
                     u16* __restrict__ yl) {
    const size_t row = blockIdx.x;
    const float* xr = x + row * 1024;
    const int t = threadIdx.x;

    float4 v = *(const float4*)(xr + t * 4);
    float s  = v.x + v.y + v.z + v.w;
    float ss = v.x * v.x + v.y * v.y + v.z * v.z + v.w * v.w;

#pragma unroll
    for (int off = 32; off; off >>= 1) {
        s  += __shfl_xor(s, off);
        ss += __shfl_xor(ss, off);
    }
    __shared__ float red[8];
    const int wave = t >> 6, lane = t & 63;
    if (lane == 0) { red[wave] = s; red[4 + wave] = ss; }
    __syncthreads();
    s  = red[0] + red[1] + red[2] + red[3];
    ss = red[4] + red[5] + red[6] + red[7];

    const float mu   = s * (1.0f / 1024.0f);
    const float var  = ss * (1.0f / 1024.0f) - mu * mu;
    const float rstd = rsqrtf(var + 1e-5f);

    float o[4] = {(v.x - mu) * rstd, (v.y - mu) * rstd,
                  (v.z - mu) * rstd, (v.w - mu) * rstd};
    if (g != nullptr) {
        float4 gv = *(const float4*)(g + t * 4);
        float4 bv = *(const float4*)(b + t * 4);
        o[0] = o[0] * gv.x + bv.x; o[1] = o[1] * gv.y + bv.y;
        o[2] = o[2] * gv.z + bv.z; o[3] = o[3] * gv.w + bv.w;
    }
    ushort4 vh, vl;
    split2(o[0], vh.x, vl.x); split2(o[1], vh.y, vl.y);
    split2(o[2], vh.z, vl.z); split2(o[3], vh.w, vl.w);
    *(ushort4*)(yh + row * 1024 + t * 4) = vh;
    *(ushort4*)(yl + row * 1024 + t * 4) = vl;
}

// ---------------------------------------------------------------------------
// Weight prep: W[K][N] fp32 -> transposed bf16 planes Thi/Tlo [N][K].
// ---------------------------------------------------------------------------
__global__ __launch_bounds__(256)
void split_t_kernel(const float* __restrict__ W, u16* __restrict__ Thi,
                    u16* __restrict__ Tlo, int K, int N) {
    __shared__ float tile[64][65];
    const int bn = blockIdx.x, bk = blockIdx.y;
    const int t = threadIdx.x;
    const int col = t & 63, rquad = t >> 6;

#pragma unroll
    for (int rep = 0; rep < 16; ++rep) {
        const int row = rep * 4 + rquad;
        tile[row][col] = W[(size_t)(bk * 64 + row) * N + bn * 64 + col];
    }
    __syncthreads();
#pragma unroll
    for (int rep = 0; rep < 16; ++rep) {
        const int n = rep * 4 + rquad;
        const int k = col;
        u16 h, l;
        split2(tile[k][n], h, l);
        const size_t o = (size_t)(bn * 64 + n) * K + bk * 64 + k;
        Thi[o] = h; Tlo[o] = l;
    }
}

// ---------------------------------------------------------------------------
// Split-bf16 MFMA GEMM (m97 structure): C = (Ah+Al) @ (Bh+Bl)^T.
// Tiles [128][32] u16 unpadded, staged via global_load_lds (16B/lane),
// single-buffered; per K-step: barrier / ds_read frags / barrier /
// STAGE(next) overlapped with 48 MFMAs.
// ---------------------------------------------------------------------------
template<bool RELU, bool RES, bool ACCUM, bool SPLIT_OUT, bool TRANSV>
__global__ __launch_bounds__(256)
void mgemm(const u16* __restrict__ Ah, const u16* __restrict__ Al,
           const u16* __restrict__ Bh, const u16* __restrict__ Bl,
           const float* __restrict__ bias, const float* __restrict__ R,
           float* __restrict__ C, u16* __restrict__ Chi, u16* __restrict__ Clo,
           int M, int N, int K, int ldb) {
    __shared__ u16 Ahs[128 * 32];
    __shared__ u16 Als[128 * 32];
    __shared__ u16 Bhs[128 * 32];
    __shared__ u16 Bls[128 * 32];

    const int tid  = threadIdx.x;
    const int lane = tid & 63;
    const int wid  = tid >> 6;
    const int wr = wid >> 1, wc = wid & 1;       // wave grid 2x2, 64x64 each
    const int fr = lane & 15, kb = lane >> 4;    // frag row / k-block
    const int row0 = blockIdx.y * 128, col0 = blockIdx.x * 128;

    const int srow   = wid * 16 + (lane >> 2);   // 0..63
    const int scol   = (lane & 3) * 8;
    const int ldsoff = wid * 512;                // u16 per-wave offset in 4KB block

#define ST_TILE(LDS, P, BR, PST, KS)                                          \
    gload16(P + (size_t)((BR) + srow) * (PST) + (KS) + scol, LDS + ldsoff);   \
    gload16(P + (size_t)((BR) + 64 + srow) * (PST) + (KS) + scol,             \
            LDS + 2048 + ldsoff);

#define STAGE(KS)                                                             \
    ST_TILE(Ahs, Ah, row0, K, KS)                                             \
    ST_TILE(Als, Al, row0, K, KS)                                             \
    ST_TILE(Bhs, Bh, col0, ldb, KS)                                           \
    ST_TILE(Bls, Bl, col0, ldb, KS)

    f32x4 acc[4][4];
#pragma unroll
    for (int i = 0; i < 4; ++i)
#pragma unroll
        for (int j = 0; j < 4; ++j)
            acc[i][j] = (f32x4){0.f, 0.f, 0.f, 0.f};

    STAGE(0)

    for (int ks = 0; ks < K; ks += 32) {
        __syncthreads();   // drains gload vmcnt -> tile visible to all waves

        bf16x8 fah[4], fal[4], fbh[4], fbl[4];
#pragma unroll
        for (int i = 0; i < 4; ++i) {
            const int ar = (wr * 64 + i * 16 + fr) * 32 + kb * 8;
            fah[i] = *(const bf16x8*)&Ahs[ar];
            fal[i] = *(const bf16x8*)&Als[ar];
            const int br = (wc * 64 + i * 16 + fr) * 32 + kb * 8;
            fbh[i] = *(const bf16x8*)&Bhs[br];
            fbl[i] = *(const bf16x8*)&Bls[br];
        }
        __syncthreads();   // all waves' ds_reads retired -> safe to overwrite

        if (ks + 32 < K) { STAGE(ks + 32) }   // overlaps with MFMA below

#pragma unroll
        for (int mi = 0; mi < 4; ++mi)
#pragma unroll
            for (int nj = 0; nj < 4; ++nj) {
                acc[mi][nj] = __builtin_amdgcn_mfma_f32_16x16x32_bf16(fah[mi], fbh[nj], acc[mi][nj], 0, 0, 0);
                acc[mi][nj] = __builtin_amdgcn_mfma_f32_16x16x32_bf16(fah[mi], fbl[nj], acc[mi][nj], 0, 0, 0);
                acc[mi][nj] = __builtin_amdgcn_mfma_f32_16x16x32_bf16(fal[mi], fbh[nj], acc[mi][nj], 0, 0, 0);
            }
    }
#undef STAGE
#undef ST_TILE

    // Epilogue. C/D frag: col = lane&15, row = (lane>>4)*4 + i.
#pragma unroll
    for (int mi = 0; mi < 4; ++mi)
#pragma unroll
        for (int nj = 0; nj < 4; ++nj) {
            const int gc = col0 + wc * 64 + nj * 16 + fr;
            const float bv = (bias != nullptr) ? bias[gc] : 0.0f;
#pragma unroll
            for (int i = 0; i < 4; ++i) {
                const int gr = row0 + wr * 64 + mi * 16 + kb * 4 + i;
                const size_t o = (size_t)gr * N + gc;
                float v2 = acc[mi][nj][i] + bv;
                if (RES)   v2 += R[o];
                if (RELU)  v2 = fmaxf(v2, 0.0f);
                if (ACCUM) v2 += C[o];
                if (SPLIT_OUT) {
                    u16 hh, ll; split2(v2, hh, ll);
                    size_t ot = o;
                    if (TRANSV) {
                        // [BL][D] -> per-head transposed [B*H][hd][L]
                        const int bb = gr >> 9, lpos = gr & 511;
                        const int hh2 = gc >> 8, dd = gc & 255;
                        ot = (((size_t)bb * 4 + hh2) * 256 + dd) * 512 + lpos;
                    }
                    Chi[ot] = hh; Clo[ot] = ll;
                } else {
                    C[o] = v2;
                }
            }
        }
}

// ---------------------------------------------------------------------------
// MFMA attention. One block = (b, h, 16-q-row tile); 4 waves.
// XCD-swizzled blockIdx so the 32 qt-blocks sharing one (b,h)'s K/V land on
// one XCD (K/V stay L2-resident; was 4x HBM over-fetch).
// Scores in LDS; P hi/lo planes overlay dead score rows (33.3 KB total).
// ---------------------------------------------------------------------------
__global__ __launch_bounds__(256)
void mfma_attn(const u16* __restrict__ qh, const u16* __restrict__ ql,
               const u16* __restrict__ kh, const u16* __restrict__ kl,
               const u16* __restrict__ vth, const u16* __restrict__ vtl,
               const float* __restrict__ cbias, const float* __restrict__ sharp,
               u16* __restrict__ ao_h, u16* __restrict__ ao_l,
               float* __restrict__ out_attn) {
    __shared__ float sc[16 * 520];   // 33.3 KB; P planes overlay after softmax
    u16* scU = (u16*)sc;             // row r: ph at [r*1040 + c], pl at [+520]

    const int orig = blockIdx.x;          // 2048 = 16b * 4h * 32qt
    const int blk  = ((orig & 7) << 8) | (orig >> 3);   // T1 XCD swizzle
    const int b   = blk >> 7;
    const int h   = (blk >> 5) & 3;
    const int qt  = blk & 31;
    const int t   = threadIdx.x;
    const int wid = t >> 6, lane = t & 63;
    const int fr = lane & 15, kg = lane >> 4;

    // ---- Q fragments to registers: rows qt*16 + fr, 8 k-blocks x hi/lo ----
    bf16x8 qfh[8], qfl[8];
    {
        const size_t qoff = ((size_t)b * 512 + qt * 16 + fr) * 1024 + h * 256 + kg * 8;
#pragma unroll
        for (int kb2 = 0; kb2 < 8; ++kb2) {
            qfh[kb2] = *(const bf16x8*)(qh + qoff + kb2 * 32);
            qfl[kb2] = *(const bf16x8*)(ql + qoff + kb2 * 32);
        }
    }

    // ---- scores: wave owns key-cols [wid*128, wid*128+128), 8 col-frags ----
    const float sharp_val = sharp[0];
    for (int cf = 0; cf < 8; ++cf) {
        const int col0 = wid * 128 + cf * 16;
        const size_t koff = ((size_t)b * 512 + col0 + fr) * 1024 + h * 256 + kg * 8;
        // Batch all 16 K-frag loads (ILP), then a pure-MFMA cluster.
        bf16x8 kf_h[8], kf_l[8];
#pragma unroll
        for (int kb2 = 0; kb2 < 8; ++kb2) {
            kf_h[kb2] = *(const bf16x8*)(kh + koff + kb2 * 32);
            kf_l[kb2] = *(const bf16x8*)(kl + koff + kb2 * 32);
        }
        f32x4 acc = (f32x4){0.f, 0.f, 0.f, 0.f};
        __builtin_amdgcn_s_setprio(1);
#pragma unroll
        for (int kb2 = 0; kb2 < 8; ++kb2) {
            acc = __builtin_amdgcn_mfma_f32_16x16x32_bf16(qfh[kb2], kf_h[kb2], acc, 0, 0, 0);
            acc = __builtin_amdgcn_mfma_f32_16x16x32_bf16(qfh[kb2], kf_l[kb2], acc, 0, 0, 0);
            acc = __builtin_amdgcn_mfma_f32_16x16x32_bf16(qfl[kb2], kf_h[kb2], acc, 0, 0, 0);
        }
        __builtin_amdgcn_s_setprio(0);
        const int col = col0 + fr;        // C-frag: col = lane&15
#pragma unroll
        for (int i = 0; i < 4; ++i) {
            const int row_l = kg * 4 + i; // C-frag: row = (lane>>4)*4 + i
            float sv = acc[i] * 0.0625f;
            if (qt == 0 && row_l == 0)    // global q-row 0
                sv = (sv + cbias[col]) * sharp_val;
            sc[row_l * 520 + col] = sv;
        }
    }
    __syncthreads();

    // ---- softmax: wave w rows w*4..w*4+3; split P into overlay planes ----
#pragma unroll
    for (int rr = 0; rr < 4; ++rr) {
        const int r = wid * 4 + rr;
        float vals[8];
        float m = -1e30f;
#pragma unroll
        for (int j = 0; j < 8; ++j) {
            vals[j] = sc[r * 520 + lane + j * 64];
            m = fmaxf(m, vals[j]);
        }
#pragma unroll
        for (int off = 32; off; off >>= 1) m = fmaxf(m, __shfl_xor(m, off));
        float sum = 0.0f;
#pragma unroll
        for (int j = 0; j < 8; ++j) { vals[j] = expf(vals[j] - m); sum += vals[j]; }
#pragma unroll
        for (int off = 32; off; off >>= 1) sum += __shfl_xor(sum, off);
        const float inv = 1.0f / sum;
        float* oa = (h == 0)
            ? out_attn + ((size_t)b * 512 + qt * 16 + r) * 512 : nullptr;
#pragma unroll
        for (int j = 0; j < 8; ++j) {
            const float p = vals[j] * inv;
            const int c = lane + j * 64;
            if (oa != nullptr) oa[c] = p;
            u16 hh, ll; split2(p, hh, ll);
            scU[r * 1040 + c] = hh;          // overlays row r (already in regs)
            scU[r * 1040 + 520 + c] = ll;
        }
    }
    __syncthreads();

    // ---- PV: wave owns d-block [wid*64, wid*64+64), 4 d-frags ----
    {
        f32x4 acc4[4];
#pragma unroll
        for (int f = 0; f < 4; ++f) acc4[f] = (f32x4){0.f, 0.f, 0.f, 0.f};
        const size_t vtbase = (((size_t)b * 4 + h) * 256 + wid * 64 + fr) * 512 + kg * 8;
#pragma unroll 2
        for (int kb2 = 0; kb2 < 16; ++kb2) {
            const bf16x8 pfh = *(const bf16x8*)&scU[fr * 1040 + kb2 * 32 + kg * 8];
            const bf16x8 pfl = *(const bf16x8*)&scU[fr * 1040 + 520 + kb2 * 32 + kg * 8];
            // Batch the 8 V-frag loads, then a pure-MFMA cluster.
            bf16x8 vf_h[4], vf_l[4];
#pragma unroll
            for (int f = 0; f < 4; ++f) {
                const size_t vo = vtbase + (size_t)f * 16 * 512 + kb2 * 32;
                vf_h[f] = *(const bf16x8*)(vth + vo);
                vf_l[f] = *(const bf16x8*)(vtl + vo);
            }
            __builtin_amdgcn_s_setprio(1);
#pragma unroll
            for (int f = 0; f < 4; ++f) {
                acc4[f] = __builtin_amdgcn_mfma_f32_16x16x32_bf16(pfh, vf_h[f], acc4[f], 0, 0, 0);
                acc4[f] = __builtin_amdgcn_mfma_f32_16x16x32_bf16(pfh, vf_l[f], acc4[f], 0, 0, 0);
                acc4[f] = __builtin_amdgcn_mfma_f32_16x16x32_bf16(pfl, vf_h[f], acc4[f], 0, 0, 0);
            }
            __builtin_amdgcn_s_setprio(0);
        }
#pragma unroll
        for (int f = 0; f < 4; ++f) {
#pragma unroll
            for (int i = 0; i < 4; ++i) {
                const int row_l = kg * 4 + i;
                const size_t o = ((size_t)b * 512 + qt * 16 + row_l) * 1024
                               + h * 256 + wid * 64 + f * 16 + fr;
                u16 hh, ll; split2(acc4[f][i], hh, ll);
                ao_h[o] = hh; ao_l[o] = ll;
            }
        }
    }
}

__global__ void copy_kernel(const float* __restrict__ in, float* __restrict__ out, int n) {
    const int i = blockIdx.x * blockDim.x + threadIdx.x;
    if (i < n) out[i] = in[i];
}

// ---------------------------------------------------------------------------
// Orchestration. Workspace = 128 MiB (proven safe). Live ranges:
//   [0,16)   : wq/wk/wv/wo T-planes (2 MB each plane)
//   [16,32)  : w1T planes (hi 8 + lo 8)
//   [32,64)  : sln planes -> ao planes (after QKV) -> hid planes (after Wo)
//   [64,96)  : k planes -> w2T planes [64,80) after attention
//   [96,128) : vt planes -> hbuf planes after attention
//   q planes : parked in d_out s-region (32 MB; dead before Wo writes out_s)
// d_out: [ s (8,388,608) | z (4,096) | attn_head0 (4,194,304) ] floats.
// ---------------------------------------------------------------------------
extern "C" void kernel_launch(void* const* d_in, const int* in_sizes, int n_in,
                              void* d_out, int out_size, void* d_ws, size_t ws_size,
                              hipStream_t stream) {
    (void)in_sizes; (void)n_in; (void)out_size; (void)ws_size;

    const float* s     = (const float*)d_in[0];
    const float* z     = (const float*)d_in[1];
    const float* wq    = (const float*)d_in[2];
    const float* bq    = (const float*)d_in[3];
    const float* wk    = (const float*)d_in[4];
    const float* bk    = (const float*)d_in[5];
    const float* wv    = (const float*)d_in[6];
    const float* bv    = (const float*)d_in[7];
    const float* wo    = (const float*)d_in[8];
    const float* bo    = (const float*)d_in[9];
    const float* cbias = (const float*)d_in[10];
    const float* sharp = (const float*)d_in[11];
    const float* ln_g  = (const float*)d_in[12];
    const float* ln_b  = (const float*)d_in[13];
    const float* w1    = (const float*)d_in[14];
    const float* b1    = (const float*)d_in[15];
    const float* w2    = (const float*)d_in[16];
    const float* b2    = (const float*)d_in[17];

    const size_t MB = 1024 * 1024;
    unsigned char* wsb = (unsigned char*)d_ws;

    u16* wqT_h = (u16*)(wsb + 0 * MB);
    u16* wqT_l = (u16*)(wsb + 2 * MB);
    u16* wkT_h = (u16*)(wsb + 4 * MB);
    u16* wkT_l = (u16*)(wsb + 6 * MB);
    u16* wvT_h = (u16*)(wsb + 8 * MB);
    u16* wvT_l = (u16*)(wsb + 10 * MB);
    u16* woT_h = (u16*)(wsb + 12 * MB);
    u16* woT_l = (u16*)(wsb + 14 * MB);
    u16* w1T_h = (u16*)(wsb + 16 * MB);
    u16* w1T_l = (u16*)(wsb + 24 * MB);
    u16* sln_h = (u16*)(wsb + 32 * MB);
    u16* sln_l = (u16*)(wsb + 48 * MB);
    u16* k_h   = (u16*)(wsb + 64 * MB);
    u16* k_l   = (u16*)(wsb + 80 * MB);
    u16* vt_h  = (u16*)(wsb + 96 * MB);
    u16* vt_l  = (u16*)(wsb + 112 * MB);
    // stream-ordered reuses:
    u16* ao_h  = sln_h;                   // attn-out planes (sln dead after QKV)
    u16* ao_l  = sln_l;
    u16* w2T_h = (u16*)(wsb + 64 * MB);   // after attention (k planes dead)
    u16* w2T_l = (u16*)(wsb + 72 * MB);
    u16* hid_h = (u16*)(wsb + 32 * MB);   // hidden-quarter planes (ao dead)
    u16* hid_l = (u16*)(wsb + 48 * MB);
    u16* hb_h  = (u16*)(wsb + 96 * MB);   // LN2 planes (vt dead)
    u16* hb_l  = (u16*)(wsb + 112 * MB);

    const size_t U = (size_t)8192 * 1024;
    float* out_s    = (float*)d_out;
    float* out_z    = out_s + U;
    float* out_attn = out_z + 16 * 256;
    u16* q_h = (u16*)d_out;               // q planes parked in d_out s-region
    u16* q_l = q_h + U;

    // 1. Weight prep (w2 later, into k planes' slot)
    split_t_kernel<<<dim3(16, 16), 256, 0, stream>>>(wq, wqT_h, wqT_l, 1024, 1024);
    split_t_kernel<<<dim3(16, 16), 256, 0, stream>>>(wk, wkT_h, wkT_l, 1024, 1024);
    split_t_kernel<<<dim3(16, 16), 256, 0, stream>>>(wv, wvT_h, wvT_l, 1024, 1024);
    split_t_kernel<<<dim3(16, 16), 256, 0, stream>>>(wo, woT_h, woT_l, 1024, 1024);
    split_t_kernel<<<dim3(64, 16), 256, 0, stream>>>(w1, w1T_h, w1T_l, 1024, 4096);

    // 2. LN1 -> sln planes
    ln_split_kernel<<<8192, 256, 0, stream>>>(s, nullptr, nullptr, sln_h, sln_l);

    // 3. QKV projections -> split planes (V transposed per head)
    const dim3 gq(8, 64);
    mgemm<false, false, false, true, false><<<gq, 256, 0, stream>>>(
        sln_h, sln_l, wqT_h, wqT_l, bq, nullptr, nullptr, q_h, q_l, 8192, 1024, 1024, 1024);
    mgemm<false, false, false, true, false><<<gq, 256, 0, stream>>>(
        sln_h, sln_l, wkT_h, wkT_l, bk, nullptr, nullptr, k_h, k_l, 8192, 1024, 1024, 1024);
    mgemm<false, false, false, true, true><<<gq, 256, 0, stream>>>(
        sln_h, sln_l, wvT_h, wvT_l, bv, nullptr, nullptr, vt_h, vt_l, 8192, 1024, 1024, 1024);

    // 4. Attention: ao planes (over sln), head-0 probs -> d_out
    mfma_attn<<<2048, 256, 0, stream>>>(q_h, q_l, k_h, k_l, vt_h, vt_l,
                                        cbias, sharp, ao_h, ao_l, out_attn);

    // 5. w2 prep into k planes' dead space
    split_t_kernel<<<dim3(16, 64), 256, 0, stream>>>(w2, w2T_h, w2T_l, 4096, 1024);

    // 6. Output projection + residual: out_s = attn @ wo + bo + s (overwrites q)
    mgemm<false, true, false, false, false><<<gq, 256, 0, stream>>>(
        ao_h, ao_l, woT_h, woT_l, bo, s, out_s, nullptr, nullptr, 8192, 1024, 1024, 1024);

    // 7. LN2 -> hbuf planes
    ln_split_kernel<<<8192, 256, 0, stream>>>(out_s, ln_g, ln_b, hb_h, hb_l);

    // 8. MLP in 4 K-quarters of 1024:
    //    hid = relu(hbuf @ w1[:, j*1024:...] + b1) -> planes
    //    out_s += hid @ w2[j*1024:(j+1)*1024, :]   (+ b2 on pass 0)
    for (int j = 0; j < 4; ++j) {
        mgemm<true, false, false, true, false><<<gq, 256, 0, stream>>>(
            hb_h, hb_l, w1T_h + (size_t)j * 1024 * 1024, w1T_l + (size_t)j * 1024 * 1024,
            b1 + (size_t)j * 1024, nullptr, nullptr, hid_h, hid_l, 8192, 1024, 1024, 1024);
        mgemm<false, false, true, false, false><<<gq, 256, 0, stream>>>(
            hid_h, hid_l, w2T_h + (size_t)j * 1024, w2T_l + (size_t)j * 1024,
            (j == 0) ? b2 : nullptr, nullptr, out_s, nullptr, nullptr, 8192, 1024, 1024, 4096);
    }

    // 9. z passthrough
    copy_kernel<<<16, 256, 0, stream>>>(z, out_z, 4096);
}

// Round 8
// 905.225 us; speedup vs baseline: 1.2850x; 1.2850x over previous
//
#include <hip/hip_runtime.h>
#include <math.h>

// Problem constants: B=16, L=512, D=1024, H=4, hd=256, BL = B*L = 8192.
// Precision scheme (round 8): fp16 2-term. Weights/K/V stored as hi+lo fp16
// planes (lo = x - hi, raw scale); activations hi-only. A.(Bh+Bl) via 2 MFMAs
// => error ~2^-11 relative (fp32-noise floor here is 0.0156 absmax).

typedef _Float16 f16;
typedef __attribute__((ext_vector_type(8))) _Float16 f16x8;
typedef __attribute__((ext_vector_type(4))) _Float16 f16x4;
typedef __attribute__((ext_vector_type(4))) float f32x4;

__device__ inline f16 hi16(float x) { return (f16)x; }
__device__ inline f16 lo16(float x, f16 h) { return (f16)(x - (float)h); }

// Async global->LDS, 16 B per lane. LDS dest is wave-uniform base + lane*16.
__device__ inline void gload16(const void* g, void* l) {
    __builtin_amdgcn_global_load_lds(
        (const __attribute__((address_space(1))) void*)g,
        (__attribute__((address_space(3))) void*)l, 16, 0, 0);
}

// ---------------------------------------------------------------------------
// LayerNorm over rows of 1024 floats -> fp16 hi plane only (GEMM A operand).
// ---------------------------------------------------------------------------
__global__ __launch_bounds__(256)
void ln_f16_kernel(const float* __restrict__ x, const float* __restrict__ g,
                   const float* __restrict__ b, f16* __restrict__ yh) {
    const size_t row = blockIdx.x;
    const float* xr = x + row * 1024;
    const int t = threadIdx.x;

    float4 v = *(const float4*)(xr + t * 4);
    float s  = v.x + v.y + v.z + v.w;
    float ss = v.x * v.x + v.y * v.y + v.z * v.z + v.w * v.w;

#pragma unroll
    for (int off = 32; off; off >>= 1) {
        s  += __shfl_xor(s, off);
        ss += __shfl_xor(ss, off);
    }
    __shared__ float red[8];
    const int wave = t >> 6, lane = t & 63;
    if (lane == 0) { red[wave] = s; red[4 + wave] = ss; }
    __syncthreads();
    s  = red[0] + red[1] + red[2] + red[3];
    ss = red[4] + red[5] + red[6] + red[7];

    const float mu   = s * (1.0f / 1024.0f);
    const float var  = ss * (1.0f / 1024.0f) - mu * mu;
    const float rstd = rsqrtf(var + 1e-5f);

    float o[4] = {(v.x - mu) * rstd, (v.y - mu) * rstd,
                  (v.z - mu) * rstd, (v.w - mu) * rstd};
    if (g != nullptr) {
        float4 gv = *(const float4*)(g + t * 4);
        float4 bv = *(const float4*)(b + t * 4);
        o[0] = o[0] * gv.x + bv.x; o[1] = o[1] * gv.y + bv.y;
        o[2] = o[2] * gv.z + bv.z; o[3] = o[3] * gv.w + bv.w;
    }
    f16x4 vh = {hi16(o[0]), hi16(o[1]), hi16(o[2]), hi16(o[3])};
    *(f16x4*)(yh + row * 1024 + t * 4) = vh;
}

// ---------------------------------------------------------------------------
// Weight prep: W[K][N] fp32 -> transposed fp16 planes Thi/Tlo [N][K].
// ---------------------------------------------------------------------------
__global__ __launch_bounds__(256)
void split_t_kernel(const float* __restrict__ W, f16* __restrict__ Thi,
                    f16* __restrict__ Tlo, int K, int N) {
    __shared__ float tile[64][65];
    const int bn = blockIdx.x, bk = blockIdx.y;
    const int t = threadIdx.x;
    const int col = t & 63, rquad = t >> 6;

#pragma unroll
    for (int rep = 0; rep < 16; ++rep) {
        const int row = rep * 4 + rquad;
        tile[row][col] = W[(size_t)(bk * 64 + row) * N + bn * 64 + col];
    }
    __syncthreads();
#pragma unroll
    for (int rep = 0; rep < 16; ++rep) {
        const int n = rep * 4 + rquad;
        const int k = col;
        const float x = tile[k][n];
        const f16 h = hi16(x);
        const size_t o = (size_t)(bn * 64 + n) * K + bk * 64 + k;
        Thi[o] = h; Tlo[o] = lo16(x, h);
    }
}

// ---------------------------------------------------------------------------
// fp16 2-term MFMA GEMM: C[M,N] = A[M,K] @ (Bh+Bl)^T[N,K] (+bias)(+R)
// (ReLU)(+=C)(SPLIT_OUT: fp16 hi out, +lo if LO; TRANSV: per-head transpose).
// Tiles [128][32] fp16, staged via global_load_lds (3 tiles, 6 issues/thread),
// single-buffered m97-style 2-phase loop; 32 MFMAs / K-step.
// ---------------------------------------------------------------------------
template<bool RELU, bool RES, bool ACCUM, bool SPLIT_OUT, bool LO, bool TRANSV>
__global__ __launch_bounds__(256)
void mgemm(const f16* __restrict__ A, const f16* __restrict__ Bh,
           const f16* __restrict__ Bl, const float* __restrict__ bias,
           const float* __restrict__ R, float* __restrict__ C,
           f16* __restrict__ Chi, f16* __restrict__ Clo,
           int M, int N, int K, int ldb) {
    __shared__ f16 Ahs[128 * 32];
    __shared__ f16 Bhs[128 * 32];
    __shared__ f16 Bls[128 * 32];

    const int tid  = threadIdx.x;
    const int lane = tid & 63;
    const int wid  = tid >> 6;
    const int wr = wid >> 1, wc = wid & 1;       // wave grid 2x2, 64x64 each
    const int fr = lane & 15, kb = lane >> 4;    // frag row / k-block
    const int row0 = blockIdx.y * 128, col0 = blockIdx.x * 128;

    const int srow   = wid * 16 + (lane >> 2);   // 0..63
    const int scol   = (lane & 3) * 8;
    const int ldsoff = wid * 512;                // f16 elems; 1024 B per wave

#define ST_TILE(LDS, P, BR, PST, KS)                                          \
    gload16(P + (size_t)((BR) + srow) * (PST) + (KS) + scol, LDS + ldsoff);   \
    gload16(P + (size_t)((BR) + 64 + srow) * (PST) + (KS) + scol,             \
            LDS + 2048 + ldsoff);

#define STAGE(KS)                                                             \
    ST_TILE(Ahs, A, row0, K, KS)                                              \
    ST_TILE(Bhs, Bh, col0, ldb, KS)                                           \
    ST_TILE(Bls, Bl, col0, ldb, KS)

    f32x4 acc[4][4];
#pragma unroll
    for (int i = 0; i < 4; ++i)
#pragma unroll
        for (int j = 0; j < 4; ++j)
            acc[i][j] = (f32x4){0.f, 0.f, 0.f, 0.f};

    STAGE(0)

    for (int ks = 0; ks < K; ks += 32) {
        __syncthreads();   // drains gload vmcnt -> tile visible to all waves

        f16x8 fa[4], fbh[4], fbl[4];
#pragma unroll
        for (int i = 0; i < 4; ++i) {
            const int ar = (wr * 64 + i * 16 + fr) * 32 + kb * 8;
            fa[i] = *(const f16x8*)&Ahs[ar];
            const int br = (wc * 64 + i * 16 + fr) * 32 + kb * 8;
            fbh[i] = *(const f16x8*)&Bhs[br];
            fbl[i] = *(const f16x8*)&Bls[br];
        }
        __syncthreads();   // all waves' ds_reads retired -> safe to overwrite

        if (ks + 32 < K) { STAGE(ks + 32) }   // overlaps with MFMA below

#pragma unroll
        for (int mi = 0; mi < 4; ++mi)
#pragma unroll
            for (int nj = 0; nj < 4; ++nj) {
                acc[mi][nj] = __builtin_amdgcn_mfma_f32_16x16x32_f16(fa[mi], fbh[nj], acc[mi][nj], 0, 0, 0);
                acc[mi][nj] = __builtin_amdgcn_mfma_f32_16x16x32_f16(fa[mi], fbl[nj], acc[mi][nj], 0, 0, 0);
            }
    }
#undef STAGE
#undef ST_TILE

    // Epilogue. C/D frag: col = lane&15, row = (lane>>4)*4 + i.
#pragma unroll
    for (int mi = 0; mi < 4; ++mi)
#pragma unroll
        for (int nj = 0; nj < 4; ++nj) {
            const int gc = col0 + wc * 64 + nj * 16 + fr;
            const float bv = (bias != nullptr) ? bias[gc] : 0.0f;
#pragma unroll
            for (int i = 0; i < 4; ++i) {
                const int gr = row0 + wr * 64 + mi * 16 + kb * 4 + i;
                const size_t o = (size_t)gr * N + gc;
                float v2 = acc[mi][nj][i] + bv;
                if (RES)   v2 += R[o];
                if (RELU)  v2 = fmaxf(v2, 0.0f);
                if (ACCUM) v2 += C[o];
                if (SPLIT_OUT) {
                    size_t ot = o;
                    if (TRANSV) {
                        // [BL][D] -> per-head transposed [B*H][hd][L]
                        const int bb = gr >> 9, lpos = gr & 511;
                        const int hh2 = gc >> 8, dd = gc & 255;
                        ot = (((size_t)bb * 4 + hh2) * 256 + dd) * 512 + lpos;
                    }
                    const f16 h = hi16(v2);
                    Chi[ot] = h;
                    if (LO) Clo[ot] = lo16(v2, h);
                } else {
                    C[o] = v2;
                }
            }
        }
}

// ---------------------------------------------------------------------------
// MFMA attention (fp16 2-term). One block = (b, h, 16-q-row tile); 4 waves.
// Q hi-only in regs; K hi+lo; P hi-only (overlay in score LDS); Vt hi+lo.
// XCD-swizzled blockIdx keeps each (b,h)'s K/V in one XCD's L2.
// Per-term accumulators halve the dependent-MFMA chain depth.
// ---------------------------------------------------------------------------
__global__ __launch_bounds__(256)
void mfma_attn(const f16* __restrict__ qh, const f16* __restrict__ kh,
               const f16* __restrict__ kl, const f16* __restrict__ vth,
               const f16* __restrict__ vtl, const float* __restrict__ cbias,
               const float* __restrict__ sharp, f16* __restrict__ ao_h,
               float* __restrict__ out_attn) {
    __shared__ float sc[16 * 520];   // 33.3 KB; P hi plane overlays after softmax
    f16* scP = (f16*)sc;             // row r: P[c] at [r*1040 + c]

    const int orig = blockIdx.x;          // 2048 = 16b * 4h * 32qt
    const int blk  = ((orig & 7) << 8) | (orig >> 3);   // T1 XCD swizzle
    const int b   = blk >> 7;
    const int h   = (blk >> 5) & 3;
    const int qt  = blk & 31;
    const int t   = threadIdx.x;
    const int wid = t >> 6, lane = t & 63;
    const int fr = lane & 15, kg = lane >> 4;

    // ---- Q frags (hi only): rows qt*16 + fr, 8 k-blocks ----
    f16x8 qf[8];
    {
        const size_t qoff = ((size_t)b * 512 + qt * 16 + fr) * 1024 + h * 256 + kg * 8;
#pragma unroll
        for (int kb2 = 0; kb2 < 8; ++kb2)
            qf[kb2] = *(const f16x8*)(qh + qoff + kb2 * 32);
    }

    // ---- scores: wave owns key-cols [wid*128, +128), 8 col-frags ----
    const float sharp_val = sharp[0];
    for (int cf = 0; cf < 8; ++cf) {
        const int col0 = wid * 128 + cf * 16;
        const size_t koff = ((size_t)b * 512 + col0 + fr) * 1024 + h * 256 + kg * 8;
        f16x8 kf_h[8], kf_l[8];
#pragma unroll
        for (int kb2 = 0; kb2 < 8; ++kb2) {
            kf_h[kb2] = *(const f16x8*)(kh + koff + kb2 * 32);
            kf_l[kb2] = *(const f16x8*)(kl + koff + kb2 * 32);
        }
        f32x4 accA = (f32x4){0.f, 0.f, 0.f, 0.f};
        f32x4 accB = (f32x4){0.f, 0.f, 0.f, 0.f};
        __builtin_amdgcn_s_setprio(1);
#pragma unroll
        for (int kb2 = 0; kb2 < 8; ++kb2) {
            accA = __builtin_amdgcn_mfma_f32_16x16x32_f16(qf[kb2], kf_h[kb2], accA, 0, 0, 0);
            accB = __builtin_amdgcn_mfma_f32_16x16x32_f16(qf[kb2], kf_l[kb2], accB, 0, 0, 0);
        }
        __builtin_amdgcn_s_setprio(0);
        const int col = col0 + fr;        // C-frag: col = lane&15
#pragma unroll
        for (int i = 0; i < 4; ++i) {
            const int row_l = kg * 4 + i; // C-frag: row = (lane>>4)*4 + i
            float sv = (accA[i] + accB[i]) * 0.0625f;
            if (qt == 0 && row_l == 0)    // global q-row 0
                sv = (sv + cbias[col]) * sharp_val;
            sc[row_l * 520 + col] = sv;
        }
    }
    __syncthreads();

    // ---- softmax: wave w rows w*4..w*4+3; write P hi plane (overlay) ----
#pragma unroll
    for (int rr = 0; rr < 4; ++rr) {
        const int r = wid * 4 + rr;
        float vals[8];
        float m = -1e30f;
#pragma unroll
        for (int j = 0; j < 8; ++j) {
            vals[j] = sc[r * 520 + lane + j * 64];
            m = fmaxf(m, vals[j]);
        }
#pragma unroll
        for (int off = 32; off; off >>= 1) m = fmaxf(m, __shfl_xor(m, off));
        float sum = 0.0f;
#pragma unroll
        for (int j = 0; j < 8; ++j) { vals[j] = expf(vals[j] - m); sum += vals[j]; }
#pragma unroll
        for (int off = 32; off; off >>= 1) sum += __shfl_xor(sum, off);
        const float inv = 1.0f / sum;
        float* oa = (h == 0)
            ? out_attn + ((size_t)b * 512 + qt * 16 + r) * 512 : nullptr;
#pragma unroll
        for (int j = 0; j < 8; ++j) {
            const float p = vals[j] * inv;
            const int c = lane + j * 64;
            if (oa != nullptr) oa[c] = p;
            scP[r * 1040 + c] = hi16(p);    // overlays row r (already in regs)
        }
    }
    __syncthreads();

    // ---- PV: wave owns d-block [wid*64, +64), 4 d-frags, per-term accs ----
    {
        f32x4 aH[4], aL[4];
#pragma unroll
        for (int f = 0; f < 4; ++f) {
            aH[f] = (f32x4){0.f, 0.f, 0.f, 0.f};
            aL[f] = (f32x4){0.f, 0.f, 0.f, 0.f};
        }
        const size_t vtbase = (((size_t)b * 4 + h) * 256 + wid * 64 + fr) * 512 + kg * 8;
        for (int kb2 = 0; kb2 < 16; ++kb2) {
            const f16x8 pf = *(const f16x8*)&scP[fr * 1040 + kb2 * 32 + kg * 8];
            f16x8 vf_h[4], vf_l[4];
#pragma unroll
            for (int f = 0; f < 4; ++f) {
                const size_t vo = vtbase + (size_t)f * 16 * 512 + kb2 * 32;
                vf_h[f] = *(const f16x8*)(vth + vo);
                vf_l[f] = *(const f16x8*)(vtl + vo);
            }
            __builtin_amdgcn_s_setprio(1);
#pragma unroll
            for (int f = 0; f < 4; ++f) {
                aH[f] = __builtin_amdgcn_mfma_f32_16x16x32_f16(pf, vf_h[f], aH[f], 0, 0, 0);
                aL[f] = __builtin_amdgcn_mfma_f32_16x16x32_f16(pf, vf_l[f], aL[f], 0, 0, 0);
            }
            __builtin_amdgcn_s_setprio(0);
        }
#pragma unroll
        for (int f = 0; f < 4; ++f) {
#pragma unroll
            for (int i = 0; i < 4; ++i) {
                const int row_l = kg * 4 + i;
                const size_t o = ((size_t)b * 512 + qt * 16 + row_l) * 1024
                               + h * 256 + wid * 64 + f * 16 + fr;
                ao_h[o] = hi16(aH[f][i] + aL[f][i]);
            }
        }
    }
}

__global__ void copy_kernel(const float* __restrict__ in, float* __restrict__ out, int n) {
    const int i = blockIdx.x * blockDim.x + threadIdx.x;
    if (i < n) out[i] = in[i];
}

// ---------------------------------------------------------------------------
// Orchestration. Workspace = 128 MiB. fp16 plane sizes: act plane 16 MB,
// DxD weight plane 2 MB, w1/w2 plane 8 MB. Live ranges (stream-ordered):
//   [0,16)   : wq/wk/wv/wo T-planes (hi+lo, 2 MB each)
//   [16,32)  : w1T hi [16,24) + lo [24,32)
//   [32,48)  : sln_h -> ao_h (after QKV) -> hid_h part (after Wo)
//   [32,64)  : hid_h (8192x2048, 32 MB) during MLP
//   [64,96)  : k_h [64,80) + k_l [80,96) -> w2T hi [64,72)+lo [72,80) after attn
//   [96,128) : vt_h [96,112) + vt_l [112,128) -> hb_h [96,112) after attn
//   q_h      : parked in d_out s-region (16 MB; dead before Wo writes out_s)
// d_out: [ s (8,388,608) | z (4,096) | attn_head0 (4,194,304) ] floats.
// ---------------------------------------------------------------------------
extern "C" void kernel_launch(void* const* d_in, const int* in_sizes, int n_in,
                              void* d_out, int out_size, void* d_ws, size_t ws_size,
                              hipStream_t stream) {
    (void)in_sizes; (void)n_in; (void)out_size; (void)ws_size;

    const float* s     = (const float*)d_in[0];
    const float* z     = (const float*)d_in[1];
    const float* wq    = (const float*)d_in[2];
    const float* bq    = (const float*)d_in[3];
    const float* wk    = (const float*)d_in[4];
    const float* bk    = (const float*)d_in[5];
    const float* wv    = (const float*)d_in[6];
    const float* bv    = (const float*)d_in[7];
    const float* wo    = (const float*)d_in[8];
    const float* bo    = (const float*)d_in[9];
    const float* cbias = (const float*)d_in[10];
    const float* sharp = (const float*)d_in[11];
    const float* ln_g  = (const float*)d_in[12];
    const float* ln_b  = (const float*)d_in[13];
    const float* w1    = (const float*)d_in[14];
    const float* b1    = (const float*)d_in[15];
    const float* w2    = (const float*)d_in[16];
    const float* b2    = (const float*)d_in[17];

    const size_t MB = 1024 * 1024;
    unsigned char* wsb = (unsigned char*)d_ws;

    f16* wqT_h = (f16*)(wsb + 0 * MB);
    f16* wqT_l = (f16*)(wsb + 2 * MB);
    f16* wkT_h = (f16*)(wsb + 4 * MB);
    f16* wkT_l = (f16*)(wsb + 6 * MB);
    f16* wvT_h = (f16*)(wsb + 8 * MB);
    f16* wvT_l = (f16*)(wsb + 10 * MB);
    f16* woT_h = (f16*)(wsb + 12 * MB);
    f16* woT_l = (f16*)(wsb + 14 * MB);
    f16* w1T_h = (f16*)(wsb + 16 * MB);
    f16* w1T_l = (f16*)(wsb + 24 * MB);
    f16* sln_h = (f16*)(wsb + 32 * MB);
    f16* k_h   = (f16*)(wsb + 64 * MB);
    f16* k_l   = (f16*)(wsb + 80 * MB);
    f16* vt_h  = (f16*)(wsb + 96 * MB);
    f16* vt_l  = (f16*)(wsb + 112 * MB);
    // stream-ordered reuses:
    f16* ao_h  = sln_h;                   // attn-out hi (sln dead after QKV)
    f16* w2T_h = (f16*)(wsb + 64 * MB);   // after attention (k planes dead)
    f16* w2T_l = (f16*)(wsb + 72 * MB);
    f16* hid_h = (f16*)(wsb + 32 * MB);   // 8192x2048 half (ao dead after Wo)
    f16* hb_h  = (f16*)(wsb + 96 * MB);   // LN2 hi (vt dead)

    const size_t U = (size_t)8192 * 1024;
    float* out_s    = (float*)d_out;
    float* out_z    = out_s + U;
    float* out_attn = out_z + 16 * 256;
    f16* q_h = (f16*)d_out;               // q hi parked in d_out s-region

    // 1. Weight prep (w2 later, into k planes' slot)
    split_t_kernel<<<dim3(16, 16), 256, 0, stream>>>(wq, wqT_h, wqT_l, 1024, 1024);
    split_t_kernel<<<dim3(16, 16), 256, 0, stream>>>(wk, wkT_h, wkT_l, 1024, 1024);
    split_t_kernel<<<dim3(16, 16), 256, 0, stream>>>(wv, wvT_h, wvT_l, 1024, 1024);
    split_t_kernel<<<dim3(16, 16), 256, 0, stream>>>(wo, woT_h, woT_l, 1024, 1024);
    split_t_kernel<<<dim3(64, 16), 256, 0, stream>>>(w1, w1T_h, w1T_l, 1024, 4096);

    // 2. LN1 -> sln hi plane
    ln_f16_kernel<<<8192, 256, 0, stream>>>(s, nullptr, nullptr, sln_h);

    // 3. QKV projections: Q hi-only; K hi+lo; V hi+lo transposed per head
    const dim3 gq(8, 64);
    mgemm<false, false, false, true, false, false><<<gq, 256, 0, stream>>>(
        sln_h, wqT_h, wqT_l, bq, nullptr, nullptr, q_h, nullptr, 8192, 1024, 1024, 1024);
    mgemm<false, false, false, true, true, false><<<gq, 256, 0, stream>>>(
        sln_h, wkT_h, wkT_l, bk, nullptr, nullptr, k_h, k_l, 8192, 1024, 1024, 1024);
    mgemm<false, false, false, true, true, true><<<gq, 256, 0, stream>>>(
        sln_h, wvT_h, wvT_l, bv, nullptr, nullptr, vt_h, vt_l, 8192, 1024, 1024, 1024);

    // 4. Attention: ao hi (over sln), head-0 probs -> d_out
    mfma_attn<<<2048, 256, 0, stream>>>(q_h, k_h, k_l, vt_h, vt_l,
                                        cbias, sharp, ao_h, out_attn);

    // 5. w2 prep into k planes' dead space
    split_t_kernel<<<dim3(16, 64), 256, 0, stream>>>(w2, w2T_h, w2T_l, 4096, 1024);

    // 6. Output projection + residual: out_s = attn @ wo + bo + s (overwrites q)
    mgemm<false, true, false, false, false, false><<<gq, 256, 0, stream>>>(
        ao_h, woT_h, woT_l, bo, s, out_s, nullptr, nullptr, 8192, 1024, 1024, 1024);

    // 7. LN2 -> hb hi plane
    ln_f16_kernel<<<8192, 256, 0, stream>>>(out_s, ln_g, ln_b, hb_h);

    // 8. MLP in 2 K-halves of 2048:
    //    hid = relu(hb @ w1[:, j*2048:...] + b1) -> hi plane
    //    out_s += hid @ w2[j*2048:(j+1)*2048, :]   (+ b2 on pass 0)
    const dim3 gup(16, 64);
    for (int j = 0; j < 2; ++j) {
        mgemm<true, false, false, true, false, false><<<gup, 256, 0, stream>>>(
            hb_h, w1T_h + (size_t)j * 2048 * 1024, w1T_l + (size_t)j * 2048 * 1024,
            b1 + (size_t)j * 2048, nullptr, nullptr, hid_h, nullptr, 8192, 2048, 1024, 1024);
        mgemm<false, false, true, false, false, false><<<gq, 256, 0, stream>>>(
            hid_h, w2T_h + (size_t)j * 2048, w2T_l + (size_t)j * 2048,
            (j == 0) ? b2 : nullptr, nullptr, out_s, nullptr, nullptr, 8192, 1024, 2048, 4096);
    }

    // 9. z passthrough
    copy_kernel<<<16, 256, 0, stream>>>(z, out_z, 4096);
}